// Round 2
// baseline (1607.572 us; speedup 1.0000x reference)
//
#include <hip/hip_runtime.h>
#include <math.h>

// Problem constants
#define BB 16
#define TT 4096
#define DD 512
#define LOUT 512

// ---------------------------------------------------------------------------
// Workspace layout (bytes):
//   wt       : 786432 floats  @ 0          (conv_w repacked [tap][i][c])
//   a_pre    : 65536 floats   @ 3145728    (pre-sigmoid logits, atomicAdd target)
//   w_main   : 65536 floats   @ 3407872    (per-t main CIF weight)
//   fire_pos : 16*1024 ints   @ 3670016    (t index of fire with slot s)
//   Fcount   : 16 ints        @ 3735552
// total ~3.6 MB
// ---------------------------------------------------------------------------

__global__ void zero_ws(float* __restrict__ a_pre) {
    int idx = blockIdx.x * 256 + threadIdx.x;
    if (idx < 65536) a_pre[idx] = 0.f;
}

__global__ void repack_w(const float* __restrict__ conv_w, float* __restrict__ wt) {
    int idx = blockIdx.x * 256 + threadIdx.x;          // over 786432
    if (idx < 786432) {
        int k = idx / 262144;
        int rem = idx - k * 262144;
        int i = rem >> 9;          // /512
        int c = rem & 511;
        // conv_w[c][i][k]  ->  wt[k][i][c]
        wt[idx] = conv_w[(c * 512 + i) * 3 + k];
    }
}

// Fused conv(K=3) GEMM + ReLU + dot(out_w) partial reduction.
// Tile: BM=128 rows(t) x BN=64 cols(c), BK=32 over i, 3 taps share A tile.
// 256 threads, each owns 8x4 accumulators.
__launch_bounds__(256, 3)
__global__ void conv_gemm(const float* __restrict__ hidden,
                          const float* __restrict__ wt,
                          const float* __restrict__ conv_b,
                          const float* __restrict__ out_w,
                          float* __restrict__ a_pre) {
    __shared__ float As[32 * 132];       // [kk][rr], rr in 0..129, pad to 132
    __shared__ float Ws[3 * 32 * 64];    // [tap][kk][c]

    const int tid = threadIdx.x;
    const int tr = tid & 15;             // row group 0..15 (8 rows each)
    const int tc = tid >> 4;             // col group 0..15 (4 cols each)

    const int mtile = blockIdx.x;        // 0..511
    const int b  = mtile >> 5;           // 32 M-tiles per batch
    const int t0 = (mtile & 31) << 7;    // *128
    const int c0 = blockIdx.y << 6;      // *64

    float acc[8][4];
    #pragma unroll
    for (int r = 0; r < 8; r++)
        #pragma unroll
        for (int c = 0; c < 4; c++) acc[r][c] = 0.f;

    float u[4], cb[4];
    #pragma unroll
    for (int j = 0; j < 4; j++) {
        u[j]  = out_w[c0 + 4 * tc + j];
        cb[j] = conv_b[c0 + 4 * tc + j];
    }

    const float* hb = hidden + (size_t)b * TT * DD;

    for (int kc = 0; kc < 16; kc++) {
        const int i0 = kc * 32;
        // ---- stage A: rows t0-1 .. t0+128 (130 rows) x 32 i, transposed+shifted
        for (int idx = tid; idx < 1040; idx += 256) {   // 130 rows * 8 float4
            int rr = idx >> 3;
            int ci = idx & 7;
            int t = t0 - 1 + rr;                        // within-batch time
            float4 v = make_float4(0.f, 0.f, 0.f, 0.f);
            if (t >= 0 && t < TT)
                v = *(const float4*)(hb + (size_t)t * DD + i0 + 4 * ci);
            As[(4 * ci + 0) * 132 + rr] = v.x;
            As[(4 * ci + 1) * 132 + rr] = v.y;
            As[(4 * ci + 2) * 132 + rr] = v.z;
            As[(4 * ci + 3) * 132 + rr] = v.w;
        }
        // ---- stage W: 3 taps * 32 kk * 64 c = 1536 float4
        for (int idx = tid; idx < 1536; idx += 256) {
            int tap = idx / 512;
            int rem = idx - tap * 512;                  // kk*16 + cq
            int kk = rem >> 4;
            int cq = rem & 15;
            float4 v = *(const float4*)(wt + tap * 262144 + (size_t)(i0 + kk) * 512 + c0 + 4 * cq);
            *(float4*)&Ws[tap * 2048 + kk * 64 + 4 * cq] = v;
        }
        __syncthreads();

        #pragma unroll 4
        for (int kk = 0; kk < 32; kk++) {
            float af[10];
            const float* ap = &As[kk * 132 + 8 * tr];
            *(float4*)&af[0] = *(const float4*)(ap);
            *(float4*)&af[4] = *(const float4*)(ap + 4);
            *(float2*)&af[8] = *(const float2*)(ap + 8);
            float wf[3][4];
            #pragma unroll
            for (int tap = 0; tap < 3; tap++)
                *(float4*)&wf[tap][0] = *(const float4*)&Ws[tap * 2048 + kk * 64 + 4 * tc];
            #pragma unroll
            for (int tap = 0; tap < 3; tap++)
                #pragma unroll
                for (int r = 0; r < 8; r++)
                    #pragma unroll
                    for (int c = 0; c < 4; c++)
                        acc[r][c] = fmaf(af[r + tap], wf[tap][c], acc[r][c]);
        }
        __syncthreads();
    }

    // ---- epilogue: relu(y + conv_b) dot out_w, reduce across tc, atomicAdd
    float part[8];
    #pragma unroll
    for (int r = 0; r < 8; r++) {
        float s = 0.f;
        #pragma unroll
        for (int c = 0; c < 4; c++) {
            float y = acc[r][c] + cb[c];
            y = y > 0.f ? y : 0.f;
            s = fmaf(y, u[c], s);
        }
        part[r] = s;
    }
    float* red = As;                    // reuse: 128 rows * 16 = 2048 floats
    #pragma unroll
    for (int r = 0; r < 8; r++) red[(8 * tr + r) * 16 + tc] = part[r];
    __syncthreads();
    if (tid < 128) {
        float s = 0.f;
        #pragma unroll
        for (int j = 0; j < 16; j++) s += red[tid * 16 + j];
        atomicAdd(&a_pre[b * TT + t0 + tid], s);
    }
}

// Per-batch: sigmoid -> token_num -> rescale -> sequential CIF scan.
__global__ void cif_scan(const float* __restrict__ a_pre,
                         const float* __restrict__ mask,
                         const float* __restrict__ tll,
                         const float* __restrict__ out_bias,
                         float* __restrict__ out_tn,
                         float* __restrict__ out_alphas,
                         float* __restrict__ out_peak,
                         float* __restrict__ w_main,
                         int* __restrict__ fire_pos,
                         int* __restrict__ Fcount) {
    __shared__ float alpha_s[TT];
    __shared__ float wm_s[TT];
    __shared__ float fires_s[TT];
    __shared__ int   fp_s[1024];
    __shared__ double red[256];
    __shared__ float ratio_s;
    __shared__ int   F_sh;

    const int b = blockIdx.x;
    const int tid = threadIdx.x;
    const float ob = out_bias[0];

    double lsum = 0.0;
    for (int t = tid; t < TT; t += 256) {
        float a = a_pre[b * TT + t] + ob;
        float e = expf(-fabsf(a));
        float sg = (a >= 0.f) ? (1.f / (1.f + e)) : (e / (1.f + e));
        float af = sg * 1.0f - 0.0f;                 // SMOOTH_FACTOR / NOISE_THRESHOLD
        af = af > 0.f ? af : 0.f;
        af = af * mask[b * TT + t];
        alpha_s[t] = af;
        lsum += (double)af;
    }
    red[tid] = lsum;
    __syncthreads();
    for (int off = 128; off > 0; off >>= 1) {
        if (tid < off) red[tid] += red[tid + off];
        __syncthreads();
    }
    if (tid == 0) {
        float tn = (float)red[0];
        out_tn[b] = tn;
        ratio_s = tll[b] / tn;
    }
    __syncthreads();
    const float ratio = ratio_s;
    for (int t = tid; t < TT; t += 256) {
        float a = alpha_s[t] * ratio;
        alpha_s[t] = a;
        out_alphas[b * TT + t] = a;
    }
    __syncthreads();

    if (tid == 0) {
        float I = 0.f;
        int F = 0;
        for (int t = 0; t < TT; t++) {
            float a = alpha_s[t];
            float In = I + a;
            fires_s[t] = In;
            bool fire = (In >= 1.0f);
            float dist = 1.0f - I;
            wm_s[t] = fire ? dist : a;
            if (fire) {
                if (F < 1024) fp_s[F] = t;
                F++;
                I = In - 1.0f;
            } else {
                I = In;
            }
        }
        F_sh = (F > 1024) ? 1024 : F;
        Fcount[b] = F_sh;
    }
    __syncthreads();
    const int F = F_sh;
    for (int t = tid; t < TT; t += 256) {
        out_peak[b * TT + t] = fires_s[t];
        w_main[b * TT + t]   = wm_s[t];
    }
    for (int s = tid; s < F; s += 256)
        fire_pos[b * 1024 + s] = fp_s[s];
}

// acoustic_embeds[b,s,:] = spill(prev fire) + sum of main weights over the
// contiguous t-segment ending at fire_pos[s].
__global__ void cif_scatter(const float* __restrict__ hidden,
                            const float* __restrict__ alphas,   // scaled (in d_out)
                            const float* __restrict__ w_main,
                            const int* __restrict__ fire_pos,
                            const int* __restrict__ Fcount,
                            float* __restrict__ out_emb) {
    const int s = blockIdx.x;      // 0..511
    const int b = blockIdx.y;      // 0..15
    const int tid = threadIdx.x;   // 0..127 -> d = 4*tid
    const int F = Fcount[b];

    float4 acc = make_float4(0.f, 0.f, 0.f, 0.f);
    if (s < F) {
        const int t_hi = fire_pos[b * 1024 + s];
        const int t_lo = (s > 0) ? fire_pos[b * 1024 + s - 1] : 0;
        for (int t = t_lo; t <= t_hi; t++) {
            float w;
            if (s > 0 && t == t_lo)
                w = alphas[b * TT + t] - w_main[b * TT + t];   // remainds (spill)
            else
                w = w_main[b * TT + t];
            const float4 h = *(const float4*)(hidden + ((size_t)(b * TT + t)) * DD + 4 * tid);
            acc.x = fmaf(w, h.x, acc.x);
            acc.y = fmaf(w, h.y, acc.y);
            acc.z = fmaf(w, h.z, acc.z);
            acc.w = fmaf(w, h.w, acc.w);
        }
    }
    *(float4*)(out_emb + ((size_t)(b * LOUT + s)) * DD + 4 * tid) = acc;
}

extern "C" void kernel_launch(void* const* d_in, const int* in_sizes, int n_in,
                              void* d_out, int out_size, void* d_ws, size_t ws_size,
                              hipStream_t stream) {
    const float* hidden  = (const float*)d_in[0];   // (16,4096,512)
    const float* mask    = (const float*)d_in[1];   // (16,1,4096)
    const float* tll     = (const float*)d_in[2];   // (16,1)
    const float* conv_w  = (const float*)d_in[3];   // (512,512,3)
    const float* conv_b  = (const float*)d_in[4];   // (512,)
    const float* out_w   = (const float*)d_in[5];   // (1,512)
    const float* out_b   = (const float*)d_in[6];   // (1,)

    float* out        = (float*)d_out;
    float* out_emb    = out;                         // 16*512*512
    float* out_tn     = out + 4194304;               // 16
    float* out_alphas = out + 4194320;               // 16*4096
    float* out_peak   = out + 4259856;               // 16*4096

    char* ws = (char*)d_ws;
    float* wt       = (float*)(ws);                  // 786432 f
    float* a_pre    = (float*)(ws + 3145728);        // 65536 f
    float* w_main   = (float*)(ws + 3407872);        // 65536 f
    int*   fire_pos = (int*)(ws + 3670016);          // 16*1024 int
    int*   Fcount   = (int*)(ws + 3735552);          // 16 int

    zero_ws<<<256, 256, 0, stream>>>(a_pre);
    repack_w<<<3072, 256, 0, stream>>>(conv_w, wt);
    conv_gemm<<<dim3(512, 8), 256, 0, stream>>>(hidden, wt, conv_b, out_w, a_pre);
    cif_scan<<<16, 256, 0, stream>>>(a_pre, mask, tll, out_b,
                                     out_tn, out_alphas, out_peak,
                                     w_main, fire_pos, Fcount);
    cif_scatter<<<dim3(512, 16), 128, 0, stream>>>(hidden, out_alphas, w_main,
                                                   fire_pos, Fcount, out_emb);
}